// Round 3
// baseline (184.460 us; speedup 1.0000x reference)
//
#include <hip/hip_runtime.h>
#include <hip/hip_bf16.h>
#include <math.h>

#define S_ 3
#define G_ 8
#define B_ 2048
#define C_ 512
#define P_ 64
#define N_ (S_ * G_ * B_)   // 49152

typedef __attribute__((ext_vector_type(8))) short short8;
typedef __attribute__((ext_vector_type(4))) float f32x4;
typedef __attribute__((ext_vector_type(4))) unsigned int uint4v;

// bf16 pair pack via compiler-native path -> v_cvt_pk_bf16_f32 (RNE, same as
// the manual round-and-shift it replaces; ~1 VALU op instead of ~7).
__device__ __forceinline__ unsigned pk2(float a, float b) {
    union { __hip_bfloat162 h; unsigned u; } c;
    c.h = __float22bfloat162_rn(make_float2(a, b));
    return c.u;
}
// async global->LDS, 16B/lane; LDS dest = wave-uniform base + lane*16
__device__ __forceinline__ void gl_lds16(const void* g, void* l) {
    __builtin_amdgcn_global_load_lds(
        (const __attribute__((address_space(1))) void*)g,
        (__attribute__((address_space(3))) void*)l, 16, 0, 0);
}
#define WAIT6_BARRIER() asm volatile("s_waitcnt vmcnt(6)\n\ts_barrier" ::: "memory")
#define WAIT0_BARRIER() asm volatile("s_waitcnt vmcnt(0)\n\ts_barrier" ::: "memory")
#define RAW_BARRIER()   asm volatile("s_barrier" ::: "memory")

// ---------------------------------------------------------------------------
// prep2: w -> bf16 row-major, csq[p], rbeta[p] = 1/sigmoid(sf); ALSO zeros
// the outputs region (16 KB per block) so no separate zero kernel is needed.
// ---------------------------------------------------------------------------
__global__ __launch_bounds__(64) void prep2_kernel(
    const float* __restrict__ w, const float* __restrict__ sf,
    unsigned short* __restrict__ wb, float* __restrict__ csq,
    float* __restrict__ rbeta, float* __restrict__ out)
{
    const int p = blockIdx.x, l = threadIdx.x;

    // zero out-slice: 4096 floats per block
    f32x4* oz = (f32x4*)(out + (size_t)p * 4096);
#pragma unroll
    for (int i = 0; i < 16; ++i) oz[i * 64 + l] = (f32x4){0.f, 0.f, 0.f, 0.f};

    const float* wr = w + (size_t)p * C_ + l * 8;
    f32x4 a = *(const f32x4*)wr;
    f32x4 b = *(const f32x4*)(wr + 4);
    float s = a[0]*a[0] + a[1]*a[1] + a[2]*a[2] + a[3]*a[3]
            + b[0]*b[0] + b[1]*b[1] + b[2]*b[2] + b[3]*b[3];
    uint4v pk;
    pk.x = pk2(a[0], a[1]); pk.y = pk2(a[2], a[3]);
    pk.z = pk2(b[0], b[1]); pk.w = pk2(b[2], b[3]);
    *(uint4v*)&wb[(size_t)p * C_ + l * 8] = pk;
#pragma unroll
    for (int off = 1; off < 64; off <<= 1) s += __shfl_xor(s, off, 64);
    if (l == 0) csq[p] = s;
    if (p == 0) rbeta[l] = 1.0f + expf(-sf[l]);
}

// ---------------------------------------------------------------------------
// assign_v10: x via per-lane register double-buffer (no LDS; zero cross-wave
// reuse), w via gl_lds double-buffer. LDS only 17.7 KB, so occupancy is
// VGPR-capped: __launch_bounds__(256,4) forces VGPR<=128 -> 4 blocks/CU
// (16 waves) for latency hiding, vs 3 blocks under the old (256,3) bound.
// Math value-identical to v9.
// ---------------------------------------------------------------------------
__global__ __launch_bounds__(256, 4) void assign_v10(
    const float* __restrict__ x, const unsigned short* __restrict__ wb,
    const float* __restrict__ csq, const float* __restrict__ rbeta,
    float* __restrict__ assign, unsigned short* __restrict__ a_t)
{
    __shared__ __align__(16) float lgbuf[64 * 68];   // 17408 B epilogue scratch
    auto wsb = (unsigned short (*)[64 * 64])lgbuf;   // bytes [0,16384) alias: w dbuf
    float* lg = lgbuf;
    __shared__ float xsq_s[64];

    const int t = threadIdx.x, lane = t & 63, wv = t >> 6;
    const int q = lane >> 4, col = lane & 15;
    const int n0 = blockIdx.x * 64;

    // per-lane A-fragment source: row = 16*wv + col, k-base = q*8
    const float* gxr = x + (size_t)(n0 + 16 * wv + col) * C_ + (q * 8);

    const unsigned short* gw[2];
#pragma unroll
    for (int i = 0; i < 2; ++i) {
        const int p = 16 * wv + 8 * i + (lane >> 3);
        gw[i] = wb + (size_t)p * C_ + (((lane & 7) ^ (p & 7)) * 8);
    }
    const int wg = col & 7;

    float csqv[4], rbv[4];
#pragma unroll
    for (int nt = 0; nt < 4; ++nt) {
        csqv[nt] = csq[16 * nt + col];
        rbv[nt]  = rbeta[16 * nt + col];
    }

    f32x4 acc[4];
#pragma unroll
    for (int nt = 0; nt < 4; ++nt) acc[nt] = (f32x4){0.f, 0.f, 0.f, 0.f};
    float xsq = 0.f;

    // register double-buffer for x fragments: [buf][2*s + half]
    f32x4 xr[2][4];
    xr[0][0] = *(const f32x4*)(gxr + 0);
    xr[0][1] = *(const f32x4*)(gxr + 4);
    xr[0][2] = *(const f32x4*)(gxr + 32);
    xr[0][3] = *(const f32x4*)(gxr + 36);
#pragma unroll
    for (int i = 0; i < 2; ++i) gl_lds16(gw[i], &wsb[0][(16 * wv + 8 * i) * 64]);

#pragma unroll
    for (int ch = 0; ch < 8; ++ch) {
        const int cur = ch & 1;
        if (ch < 7) {
            const int k0 = (ch + 1) * 64;
            xr[cur ^ 1][0] = *(const f32x4*)(gxr + k0);
            xr[cur ^ 1][1] = *(const f32x4*)(gxr + k0 + 4);
            xr[cur ^ 1][2] = *(const f32x4*)(gxr + k0 + 32);
            xr[cur ^ 1][3] = *(const f32x4*)(gxr + k0 + 36);
#pragma unroll
            for (int i = 0; i < 2; ++i)
                gl_lds16(gw[i] + k0, &wsb[cur ^ 1][(16 * wv + 8 * i) * 64]);
            WAIT6_BARRIER();
        } else {
            WAIT0_BARRIER();
        }
#pragma unroll
        for (int s = 0; s < 2; ++s) {
            f32x4 f0 = xr[cur][2 * s + 0];
            f32x4 f1 = xr[cur][2 * s + 1];
            xsq += f0.x*f0.x + f0.y*f0.y + f0.z*f0.z + f0.w*f0.w
                 + f1.x*f1.x + f1.y*f1.y + f1.z*f1.z + f1.w*f1.w;
            union { uint4v u; short8 s8; } cv;
            cv.u.x = pk2(f0.x, f0.y); cv.u.y = pk2(f0.z, f0.w);
            cv.u.z = pk2(f1.x, f1.y); cv.u.w = pk2(f1.z, f1.w);
            const int wgr = 4 * s + q;
#pragma unroll
            for (int nt = 0; nt < 4; ++nt) {
                short8 bf = *(const short8*)&wsb[cur][(16 * nt + col) * 64 + ((wgr ^ wg) * 8)];
                acc[nt] = __builtin_amdgcn_mfma_f32_16x16x32_bf16(cv.s8, bf, acc[nt], 0, 0, 0);
            }
        }
        RAW_BARRIER();
    }

    xsq += __shfl_xor(xsq, 16, 64);
    xsq += __shfl_xor(xsq, 32, 64);
    if (q == 0) xsq_s[16 * wv + col] = xsq;
    __syncthreads();

    float vals[4][4];
#pragma unroll
    for (int reg = 0; reg < 4; ++reg) {
        const int row = 16 * wv + 4 * q + reg;
        const float xq = xsq_s[row];
        float vmax = -3.4e38f;
#pragma unroll
        for (int nt = 0; nt < 4; ++nt) {
            float v = 2.0f * acc[nt][reg] - xq - csqv[nt];
            v = fminf(v, 0.0f) * rbv[nt];
            vals[reg][nt] = v;
            vmax = fmaxf(vmax, v);
        }
#pragma unroll
        for (int off = 1; off < 16; off <<= 1)
            vmax = fmaxf(vmax, __shfl_xor(vmax, off, 64));
        float ss = 0.f;
#pragma unroll
        for (int nt = 0; nt < 4; ++nt) { vals[reg][nt] = __expf(vals[reg][nt] - vmax); ss += vals[reg][nt]; }
#pragma unroll
        for (int off = 1; off < 16; off <<= 1)
            ss += __shfl_xor(ss, off, 64);
        const float inv = 1.0f / ss;
#pragma unroll
        for (int nt = 0; nt < 4; ++nt) vals[reg][nt] *= inv;
    }

#pragma unroll
    for (int reg = 0; reg < 4; ++reg) {
        const int row = 16 * wv + 4 * q + reg;
#pragma unroll
        for (int nt = 0; nt < 4; ++nt)
            lg[row * 68 + 16 * nt + col] = vals[reg][nt];
    }
    __syncthreads();

#pragma unroll
    for (int i = 0; i < 4; ++i) {
        const int f = i * 256 + t;
        const int row = f >> 4, sp = (f & 15) * 4;
        *(f32x4*)(assign + (size_t)(n0 + row) * P_ + sp) = *(const f32x4*)&lg[row * 68 + sp];
    }

    const int p = lane;
    float v[16];
#pragma unroll
    for (int i = 0; i < 16; ++i) v[i] = lg[(wv * 16 + i) * 68 + p];
    uint4v d0, d1;
    d0.x = pk2(v[0], v[1]);   d0.y = pk2(v[2], v[3]);
    d0.z = pk2(v[4], v[5]);   d0.w = pk2(v[6], v[7]);
    d1.x = pk2(v[8], v[9]);   d1.y = pk2(v[10], v[11]);
    d1.z = pk2(v[12], v[13]); d1.w = pk2(v[14], v[15]);
    unsigned short* dst = a_t + (size_t)p * N_ + n0 + wv * 16;
    *(uint4v*)dst = d0;
    *(uint4v*)(dst + 8) = d1;
}

// ---------------------------------------------------------------------------
// group_v8: out[g,p,c] += sum_n a[n,p] x[n,c]. Grid (8 g, 8 ct, 6 splits),
// 384 blocks x 1024 rows (16 chunks of 64). gl_lds double-buffer pipeline;
// epilogue = direct atomicAdd into out (1.57 M atomics, no reduce kernel).
// 48 KB LDS caps occupancy at 3 blocks/CU regardless of VGPRs -> keep (256,3).
// ---------------------------------------------------------------------------
__global__ __launch_bounds__(256, 3) void group_v8(
    const float* __restrict__ x, const unsigned short* __restrict__ a_t,
    float* __restrict__ out)
{
    __shared__ __align__(16) float xsb[2][64 * 64];           // 32 KB
    __shared__ __align__(16) unsigned short asb[2][64 * 64];  // 16 KB

    const int t = threadIdx.x, lane = t & 63, wv = t >> 6;
    const int q = lane >> 4, col = lane & 15;
    const int g = blockIdx.x, ct = blockIdx.y, ws = blockIdx.z;   // 0..5
    const int c0 = ct * 64;
    const int sc = ws >> 1, b0 = (ws & 1) * 1024;
    const size_t base = (size_t)sc * (G_ * B_) + (size_t)g * B_ + b0;

    const float* gx[4];
#pragma unroll
    for (int i = 0; i < 4; ++i) {
        const int n  = 16 * wv + 4 * i + (lane >> 4);
        const int pm = ((n >> 3) & 3) | (((n >> 3) & 1) << 2);
        gx[i] = x + (base + n) * C_ + c0 + (((lane & 15) ^ pm) << 2);
    }
    const unsigned short* ga[2];
#pragma unroll
    for (int i = 0; i < 2; ++i) {
        const int p = 16 * wv + 8 * i + (lane >> 3);
        ga[i] = a_t + (size_t)p * N_ + base + (((lane & 7) ^ (p & 7)) * 8);
    }
    const int cl = 16 * wv + col;
    const int permq = q | ((q & 1) << 2);
    const int cswz  = (((cl >> 2) ^ permq) << 2) | (cl & 3);
    const int ag    = col & 7;

    f32x4 acc[4];
#pragma unroll
    for (int mt = 0; mt < 4; ++mt) acc[mt] = (f32x4){0.f, 0.f, 0.f, 0.f};

#pragma unroll
    for (int i = 0; i < 4; ++i) gl_lds16(gx[i], &xsb[0][(16 * wv + 4 * i) * 64]);
#pragma unroll
    for (int i = 0; i < 2; ++i) gl_lds16(ga[i], &asb[0][(16 * wv + 8 * i) * 64]);

#pragma unroll 2
    for (int ch = 0; ch < 16; ++ch) {
        const int cur = ch & 1;
        if (ch < 15) {
            const int nb = (ch + 1) * 64;
#pragma unroll
            for (int i = 0; i < 4; ++i)
                gl_lds16(gx[i] + (size_t)nb * C_, &xsb[cur ^ 1][(16 * wv + 4 * i) * 64]);
#pragma unroll
            for (int i = 0; i < 2; ++i)
                gl_lds16(ga[i] + nb, &asb[cur ^ 1][(16 * wv + 8 * i) * 64]);
            WAIT6_BARRIER();
        } else {
            WAIT0_BARRIER();
        }
#pragma unroll
        for (int s = 0; s < 2; ++s) {
            const int koff = s * 32 + q * 8;
            float gv[8];
#pragma unroll
            for (int j = 0; j < 8; ++j) gv[j] = xsb[cur][(koff + j) * 64 + cswz];
            union { uint4v u; short8 s8; } cv;
            cv.u.x = pk2(gv[0], gv[1]); cv.u.y = pk2(gv[2], gv[3]);
            cv.u.z = pk2(gv[4], gv[5]); cv.u.w = pk2(gv[6], gv[7]);
            const int agr = 4 * s + q;
#pragma unroll
            for (int mt = 0; mt < 4; ++mt) {
                short8 af = *(const short8*)&asb[cur][(16 * mt + col) * 64 + ((agr ^ ag) * 8)];
                acc[mt] = __builtin_amdgcn_mfma_f32_16x16x32_bf16(af, cv.s8, acc[mt], 0, 0, 0);
            }
        }
        RAW_BARRIER();
    }

    // direct atomic accumulation into out (zeroed by prep2)
    float* og = out + (size_t)g * (P_ * C_);
#pragma unroll
    for (int mt = 0; mt < 4; ++mt)
#pragma unroll
        for (int reg = 0; reg < 4; ++reg) {
            const int p = 16 * mt + 4 * q + reg;
            atomicAdd(&og[p * C_ + c0 + cl], acc[mt][reg]);
        }
}

// ---------------------------------------------------------------------------
extern "C" void kernel_launch(void* const* d_in, const int* in_sizes, int n_in,
                              void* d_out, int out_size, void* d_ws, size_t ws_size,
                              hipStream_t stream) {
    const float* x  = (const float*)d_in[0];   // node_feats [3, 16384, 512]
    const float* w  = (const float*)d_in[1];   // weight [64, 512]
    const float* sf = (const float*)d_in[2];   // smooth_factor [64]

    float* out    = (float*)d_out;              // outputs [8, 64, 512]
    float* assign = out + (size_t)G_ * P_ * C_; // assign [N, 64] fp32

    unsigned short* wb    = (unsigned short*)d_ws;                   // 64 KB
    float*          csq   = (float*)((char*)d_ws + 65536);           // 256 B
    float*          rbeta = (float*)((char*)d_ws + 65792);           // 256 B
    unsigned short* a_t   = (unsigned short*)((char*)d_ws + 66048);  // 6.29 MB

    prep2_kernel<<<P_, 64, 0, stream>>>(w, sf, wb, csq, rbeta, out);
    assign_v10<<<N_ / 64, 256, 0, stream>>>(x, wb, csq, rbeta, assign, a_t);
    dim3 gridB(G_, C_ / 64, 6);
    group_v8<<<gridB, 256, 0, stream>>>(x, a_t, out);
}

// Round 4
// 180.836 us; speedup vs baseline: 1.0200x; 1.0200x over previous
//
#include <hip/hip_runtime.h>
#include <hip/hip_bf16.h>
#include <math.h>

#define S_ 3
#define G_ 8
#define B_ 2048
#define C_ 512
#define P_ 64
#define N_ (S_ * G_ * B_)   // 49152

typedef __attribute__((ext_vector_type(8))) short short8;
typedef __attribute__((ext_vector_type(4))) float f32x4;
typedef __attribute__((ext_vector_type(4))) unsigned int uint4v;

// bf16 pair pack via compiler-native path -> v_cvt_pk_bf16_f32 (RNE, same
// rounding as the manual round-and-shift it replaced).
__device__ __forceinline__ unsigned pk2(float a, float b) {
    union { __hip_bfloat162 h; unsigned u; } c;
    c.h = __float22bfloat162_rn(make_float2(a, b));
    return c.u;
}
// async global->LDS, 16B/lane; LDS dest = wave-uniform base + lane*16
__device__ __forceinline__ void gl_lds16(const void* g, void* l) {
    __builtin_amdgcn_global_load_lds(
        (const __attribute__((address_space(1))) void*)g,
        (__attribute__((address_space(3))) void*)l, 16, 0, 0);
}
#define WAIT12_BARRIER() asm volatile("s_waitcnt vmcnt(12)\n\ts_barrier" ::: "memory")
#define WAIT6_BARRIER()  asm volatile("s_waitcnt vmcnt(6)\n\ts_barrier" ::: "memory")
#define WAIT0_BARRIER()  asm volatile("s_waitcnt vmcnt(0)\n\ts_barrier" ::: "memory")
#define RAW_BARRIER()    asm volatile("s_barrier" ::: "memory")

// ---------------------------------------------------------------------------
// prep2: w -> bf16 row-major, csq[p], rbeta[p] = 1/sigmoid(sf); ALSO zeros
// the outputs region (16 KB per block) so no separate zero kernel is needed.
// ---------------------------------------------------------------------------
__global__ __launch_bounds__(64) void prep2_kernel(
    const float* __restrict__ w, const float* __restrict__ sf,
    unsigned short* __restrict__ wb, float* __restrict__ csq,
    float* __restrict__ rbeta, float* __restrict__ out)
{
    const int p = blockIdx.x, l = threadIdx.x;

    // zero out-slice: 4096 floats per block
    f32x4* oz = (f32x4*)(out + (size_t)p * 4096);
#pragma unroll
    for (int i = 0; i < 16; ++i) oz[i * 64 + l] = (f32x4){0.f, 0.f, 0.f, 0.f};

    const float* wr = w + (size_t)p * C_ + l * 8;
    f32x4 a = *(const f32x4*)wr;
    f32x4 b = *(const f32x4*)(wr + 4);
    float s = a[0]*a[0] + a[1]*a[1] + a[2]*a[2] + a[3]*a[3]
            + b[0]*b[0] + b[1]*b[1] + b[2]*b[2] + b[3]*b[3];
    uint4v pk;
    pk.x = pk2(a[0], a[1]); pk.y = pk2(a[2], a[3]);
    pk.z = pk2(b[0], b[1]); pk.w = pk2(b[2], b[3]);
    *(uint4v*)&wb[(size_t)p * C_ + l * 8] = pk;
#pragma unroll
    for (int off = 1; off < 64; off <<= 1) s += __shfl_xor(s, off, 64);
    if (l == 0) csq[p] = s;
    if (p == 0) rbeta[l] = 1.0f + expf(-sf[l]);
}

// ---------------------------------------------------------------------------
// assign_v11: x via per-lane register ring (no LDS; zero cross-wave reuse),
// w via gl_lds ring. NEW vs v9: 2-deep pipeline (3-slot x ring + 3-buffer w
// LDS ring, steady-state vmcnt(12)) so every HBM load gets TWO chunks of
// MFMA cover instead of one (x is HBM-cold: the harness's 384MiB poison
// flushes L3 each iteration). Launch bound back to (256,3): the (256,4)
// experiment regressed (+2.7us, spills). Math value-identical to v9.
// FIFO accounting: per chunk issue [4 x-loads, 2 gl_lds] = 6 ops; at chunk
// ch, outstanding <= 18; vmcnt(12) retires exactly x(ch),w(ch).
// Ring overwrite of slot b is issued one RAW_BARRIER after its last read.
// ---------------------------------------------------------------------------
__global__ __launch_bounds__(256, 3) void assign_v11(
    const float* __restrict__ x, const unsigned short* __restrict__ wb,
    const float* __restrict__ csq, const float* __restrict__ rbeta,
    float* __restrict__ assign, unsigned short* __restrict__ a_t)
{
    __shared__ __align__(16) unsigned short wsb[3][64 * 64]; // 24 KB w ring
    float* lg = (float*)&wsb[0][0];  // epilogue alias [64][68] fp32 (17408 B)
    __shared__ float xsq_s[64];

    const int t = threadIdx.x, lane = t & 63, wv = t >> 6;
    const int q = lane >> 4, col = lane & 15;
    const int n0 = blockIdx.x * 64;

    // per-lane A-fragment source: row = 16*wv + col, k-base = q*8
    const float* gxr = x + (size_t)(n0 + 16 * wv + col) * C_ + (q * 8);

    const unsigned short* gw[2];
#pragma unroll
    for (int i = 0; i < 2; ++i) {
        const int p = 16 * wv + 8 * i + (lane >> 3);
        gw[i] = wb + (size_t)p * C_ + (((lane & 7) ^ (p & 7)) * 8);
    }
    const int wg = col & 7;

    float csqv[4], rbv[4];
#pragma unroll
    for (int nt = 0; nt < 4; ++nt) {
        csqv[nt] = csq[16 * nt + col];
        rbv[nt]  = rbeta[16 * nt + col];
    }

    f32x4 acc[4];
#pragma unroll
    for (int nt = 0; nt < 4; ++nt) acc[nt] = (f32x4){0.f, 0.f, 0.f, 0.f};
    float xsq = 0.f;

    // x register ring: xr[slot][2*s + half]
    f32x4 xr[3][4];
    // prologue: issue x(0), w(0), x(1), w(1) in FIFO-consistent order
    xr[0][0] = *(const f32x4*)(gxr + 0);
    xr[0][1] = *(const f32x4*)(gxr + 4);
    xr[0][2] = *(const f32x4*)(gxr + 32);
    xr[0][3] = *(const f32x4*)(gxr + 36);
#pragma unroll
    for (int i = 0; i < 2; ++i) gl_lds16(gw[i], &wsb[0][(16 * wv + 8 * i) * 64]);
    xr[1][0] = *(const f32x4*)(gxr + 64);
    xr[1][1] = *(const f32x4*)(gxr + 68);
    xr[1][2] = *(const f32x4*)(gxr + 96);
    xr[1][3] = *(const f32x4*)(gxr + 100);
#pragma unroll
    for (int i = 0; i < 2; ++i) gl_lds16(gw[i] + 64, &wsb[1][(16 * wv + 8 * i) * 64]);

#pragma unroll
    for (int ch = 0; ch < 8; ++ch) {
        const int cur = ch % 3;
        if (ch < 6) {
            const int k0 = (ch + 2) * 64;
            const int nxt = (ch + 2) % 3;
            xr[nxt][0] = *(const f32x4*)(gxr + k0);
            xr[nxt][1] = *(const f32x4*)(gxr + k0 + 4);
            xr[nxt][2] = *(const f32x4*)(gxr + k0 + 32);
            xr[nxt][3] = *(const f32x4*)(gxr + k0 + 36);
#pragma unroll
            for (int i = 0; i < 2; ++i)
                gl_lds16(gw[i] + k0, &wsb[nxt][(16 * wv + 8 * i) * 64]);
            WAIT12_BARRIER();
        } else if (ch == 6) {
            WAIT6_BARRIER();
        } else {
            WAIT0_BARRIER();
        }
#pragma unroll
        for (int s = 0; s < 2; ++s) {
            f32x4 f0 = xr[cur][2 * s + 0];
            f32x4 f1 = xr[cur][2 * s + 1];
            xsq += f0.x*f0.x + f0.y*f0.y + f0.z*f0.z + f0.w*f0.w
                 + f1.x*f1.x + f1.y*f1.y + f1.z*f1.z + f1.w*f1.w;
            union { uint4v u; short8 s8; } cv;
            cv.u.x = pk2(f0.x, f0.y); cv.u.y = pk2(f0.z, f0.w);
            cv.u.z = pk2(f1.x, f1.y); cv.u.w = pk2(f1.z, f1.w);
            const int wgr = 4 * s + q;
#pragma unroll
            for (int nt = 0; nt < 4; ++nt) {
                short8 bf = *(const short8*)&wsb[cur][(16 * nt + col) * 64 + ((wgr ^ wg) * 8)];
                acc[nt] = __builtin_amdgcn_mfma_f32_16x16x32_bf16(cv.s8, bf, acc[nt], 0, 0, 0);
            }
        }
        RAW_BARRIER();
    }

    xsq += __shfl_xor(xsq, 16, 64);
    xsq += __shfl_xor(xsq, 32, 64);
    if (q == 0) xsq_s[16 * wv + col] = xsq;
    __syncthreads();

    float vals[4][4];
#pragma unroll
    for (int reg = 0; reg < 4; ++reg) {
        const int row = 16 * wv + 4 * q + reg;
        const float xq = xsq_s[row];
        float vmax = -3.4e38f;
#pragma unroll
        for (int nt = 0; nt < 4; ++nt) {
            float v = 2.0f * acc[nt][reg] - xq - csqv[nt];
            v = fminf(v, 0.0f) * rbv[nt];
            vals[reg][nt] = v;
            vmax = fmaxf(vmax, v);
        }
#pragma unroll
        for (int off = 1; off < 16; off <<= 1)
            vmax = fmaxf(vmax, __shfl_xor(vmax, off, 64));
        float ss = 0.f;
#pragma unroll
        for (int nt = 0; nt < 4; ++nt) { vals[reg][nt] = __expf(vals[reg][nt] - vmax); ss += vals[reg][nt]; }
#pragma unroll
        for (int off = 1; off < 16; off <<= 1)
            ss += __shfl_xor(ss, off, 64);
        const float inv = 1.0f / ss;
#pragma unroll
        for (int nt = 0; nt < 4; ++nt) vals[reg][nt] *= inv;
    }

#pragma unroll
    for (int reg = 0; reg < 4; ++reg) {
        const int row = 16 * wv + 4 * q + reg;
#pragma unroll
        for (int nt = 0; nt < 4; ++nt)
            lg[row * 68 + 16 * nt + col] = vals[reg][nt];
    }
    __syncthreads();

#pragma unroll
    for (int i = 0; i < 4; ++i) {
        const int f = i * 256 + t;
        const int row = f >> 4, sp = (f & 15) * 4;
        *(f32x4*)(assign + (size_t)(n0 + row) * P_ + sp) = *(const f32x4*)&lg[row * 68 + sp];
    }

    const int p = lane;
    float v[16];
#pragma unroll
    for (int i = 0; i < 16; ++i) v[i] = lg[(wv * 16 + i) * 68 + p];
    uint4v d0, d1;
    d0.x = pk2(v[0], v[1]);   d0.y = pk2(v[2], v[3]);
    d0.z = pk2(v[4], v[5]);   d0.w = pk2(v[6], v[7]);
    d1.x = pk2(v[8], v[9]);   d1.y = pk2(v[10], v[11]);
    d1.z = pk2(v[12], v[13]); d1.w = pk2(v[14], v[15]);
    unsigned short* dst = a_t + (size_t)p * N_ + n0 + wv * 16;
    *(uint4v*)dst = d0;
    *(uint4v*)(dst + 8) = d1;
}

// ---------------------------------------------------------------------------
// group_v8: out[g,p,c] += sum_n a[n,p] x[n,c]. Grid (8 g, 8 ct, 6 splits),
// 384 blocks x 1024 rows (16 chunks of 64). gl_lds double-buffer pipeline;
// epilogue = direct atomicAdd into out (1.57 M atomics, no reduce kernel).
// x here is L3-warm (assign just streamed it), so the 1-deep pipeline has
// ample cover. 48 KB LDS caps occupancy at 3 blocks/CU -> keep (256,3).
// ---------------------------------------------------------------------------
__global__ __launch_bounds__(256, 3) void group_v8(
    const float* __restrict__ x, const unsigned short* __restrict__ a_t,
    float* __restrict__ out)
{
    __shared__ __align__(16) float xsb[2][64 * 64];           // 32 KB
    __shared__ __align__(16) unsigned short asb[2][64 * 64];  // 16 KB

    const int t = threadIdx.x, lane = t & 63, wv = t >> 6;
    const int q = lane >> 4, col = lane & 15;
    const int g = blockIdx.x, ct = blockIdx.y, ws = blockIdx.z;   // 0..5
    const int c0 = ct * 64;
    const int sc = ws >> 1, b0 = (ws & 1) * 1024;
    const size_t base = (size_t)sc * (G_ * B_) + (size_t)g * B_ + b0;

    const float* gx[4];
#pragma unroll
    for (int i = 0; i < 4; ++i) {
        const int n  = 16 * wv + 4 * i + (lane >> 4);
        const int pm = ((n >> 3) & 3) | (((n >> 3) & 1) << 2);
        gx[i] = x + (base + n) * C_ + c0 + (((lane & 15) ^ pm) << 2);
    }
    const unsigned short* ga[2];
#pragma unroll
    for (int i = 0; i < 2; ++i) {
        const int p = 16 * wv + 8 * i + (lane >> 3);
        ga[i] = a_t + (size_t)p * N_ + base + (((lane & 7) ^ (p & 7)) * 8);
    }
    const int cl = 16 * wv + col;
    const int permq = q | ((q & 1) << 2);
    const int cswz  = (((cl >> 2) ^ permq) << 2) | (cl & 3);
    const int ag    = col & 7;

    f32x4 acc[4];
#pragma unroll
    for (int mt = 0; mt < 4; ++mt) acc[mt] = (f32x4){0.f, 0.f, 0.f, 0.f};

#pragma unroll
    for (int i = 0; i < 4; ++i) gl_lds16(gx[i], &xsb[0][(16 * wv + 4 * i) * 64]);
#pragma unroll
    for (int i = 0; i < 2; ++i) gl_lds16(ga[i], &asb[0][(16 * wv + 8 * i) * 64]);

#pragma unroll 2
    for (int ch = 0; ch < 16; ++ch) {
        const int cur = ch & 1;
        if (ch < 15) {
            const int nb = (ch + 1) * 64;
#pragma unroll
            for (int i = 0; i < 4; ++i)
                gl_lds16(gx[i] + (size_t)nb * C_, &xsb[cur ^ 1][(16 * wv + 4 * i) * 64]);
#pragma unroll
            for (int i = 0; i < 2; ++i)
                gl_lds16(ga[i] + nb, &asb[cur ^ 1][(16 * wv + 8 * i) * 64]);
            WAIT6_BARRIER();
        } else {
            WAIT0_BARRIER();
        }
#pragma unroll
        for (int s = 0; s < 2; ++s) {
            const int koff = s * 32 + q * 8;
            float gv[8];
#pragma unroll
            for (int j = 0; j < 8; ++j) gv[j] = xsb[cur][(koff + j) * 64 + cswz];
            union { uint4v u; short8 s8; } cv;
            cv.u.x = pk2(gv[0], gv[1]); cv.u.y = pk2(gv[2], gv[3]);
            cv.u.z = pk2(gv[4], gv[5]); cv.u.w = pk2(gv[6], gv[7]);
            const int agr = 4 * s + q;
#pragma unroll
            for (int mt = 0; mt < 4; ++mt) {
                short8 af = *(const short8*)&asb[cur][(16 * mt + col) * 64 + ((agr ^ ag) * 8)];
                acc[mt] = __builtin_amdgcn_mfma_f32_16x16x32_bf16(af, cv.s8, acc[mt], 0, 0, 0);
            }
        }
        RAW_BARRIER();
    }

    // direct atomic accumulation into out (zeroed by prep2)
    float* og = out + (size_t)g * (P_ * C_);
#pragma unroll
    for (int mt = 0; mt < 4; ++mt)
#pragma unroll
        for (int reg = 0; reg < 4; ++reg) {
            const int p = 16 * mt + 4 * q + reg;
            atomicAdd(&og[p * C_ + c0 + cl], acc[mt][reg]);
        }
}

// ---------------------------------------------------------------------------
extern "C" void kernel_launch(void* const* d_in, const int* in_sizes, int n_in,
                              void* d_out, int out_size, void* d_ws, size_t ws_size,
                              hipStream_t stream) {
    const float* x  = (const float*)d_in[0];   // node_feats [3, 16384, 512]
    const float* w  = (const float*)d_in[1];   // weight [64, 512]
    const float* sf = (const float*)d_in[2];   // smooth_factor [64]

    float* out    = (float*)d_out;              // outputs [8, 64, 512]
    float* assign = out + (size_t)G_ * P_ * C_; // assign [N, 64] fp32

    unsigned short* wb    = (unsigned short*)d_ws;                   // 64 KB
    float*          csq   = (float*)((char*)d_ws + 65536);           // 256 B
    float*          rbeta = (float*)((char*)d_ws + 65792);           // 256 B
    unsigned short* a_t   = (unsigned short*)((char*)d_ws + 66048);  // 6.29 MB

    prep2_kernel<<<P_, 64, 0, stream>>>(w, sf, wb, csq, rbeta, out);
    assign_v11<<<N_ / 64, 256, 0, stream>>>(x, wb, csq, rbeta, assign, a_t);
    dim3 gridB(G_, C_ / 64, 6);
    group_v8<<<gridB, 256, 0, stream>>>(x, a_t, out);
}